// Round 2
// 541.464 us; speedup vs baseline: 1.9652x; 1.9652x over previous
//
#include <hip/hip_runtime.h>

// FactorizedSpectralConv2d, round 2b: all three stages on MFMA (compile fix: the gfx950
// builtin is __builtin_amdgcn_mfma_f32_16x16x16f16 — no underscore before f16).
// Stage 1 (DFT) / stage 3 (iDFT): 16x16x32 f16 MFMA as before.
// Mix stage: per-wave 16x16x16 f16 MFMA; wave wv owns modes k = {2wv, 2wv+1};
//   Z2[o'][t] += W2[k][o'][r] * Y2[k][r][t], r = 2*i_loc + {re,im},
//   W2 = [[re,-im],[im,re]] built in-register from global w (L2-resident).
// Ys layout [k][t][r] (PR=20, PK=324 halves) -> mix B-fragment = one aligned b64 read.
// Zs slot-swizzled (slot = k ^ 8*quad, reader XORs identically) to kill write conflicts.
// Chunk loop: 2 barriers; next chunk's x prefetched to regs before mix (latency hides
// under the mix MFMAs).

typedef _Float16 half8  __attribute__((ext_vector_type(8)));
typedef _Float16 half4v __attribute__((ext_vector_type(4)));
typedef _Float16 half2v __attribute__((ext_vector_type(2)));
typedef float    floatx4 __attribute__((ext_vector_type(4)));

#define TWO_PI_OVER_128 0.049087385212340517f

__device__ __forceinline__ unsigned int packh2(float a, float b) {
    half2v h; h[0] = (_Float16)a; h[1] = (_Float16)b;
    return __builtin_bit_cast(unsigned int, h);
}
__device__ __forceinline__ half8  ash8(uint4 u) { return __builtin_bit_cast(half8, u); }
__device__ __forceinline__ half4v ash4(uint2 u) { return __builtin_bit_cast(half4v, u); }

#define MFMA_K16(A,B,C) __builtin_amdgcn_mfma_f32_16x16x16f16((A),(B),(C),0,0,0)

#define YS_PK 324   // halves per k slice (16*20 + 4 pad)
#define YS_PR 20    // halves per t row  (16 r + 4 pad)

template<int BR>
__global__ __launch_bounds__(1024, 4) void spectral(const float* __restrict__ x,
                                                    const float* __restrict__ wt,
                                                    float* __restrict__ out)
{
    __shared__ uint4 Ubuf[36864 / 16];            // Xs (34816 B), later Zs (36864 B)
    __shared__ unsigned short Ys[32 * YS_PK];     // 20736 B

    unsigned short* Xs = (unsigned short*)Ubuf;
    unsigned int*   Zs = (unsigned int*)Ubuf;

    const int tid  = threadIdx.x;
    const int wv   = tid >> 6;
    const int mrow = tid & 15;
    const int quad = (tid >> 4) & 3;
    const int bx   = blockIdx.x;
    const int b    = bx >> 3;
    const int tile = bx & 7;

    const long xb = (long)b * 1048576 + (BR == 0 ? tile * 2048 : tile * 16);
    const long ob = xb;

    // ---- stage-1 A fragments: F[kp][d], kp-tile fixed per wave ----
    const int kptile = wv & 3;
    half8 Ff[4];
#pragma unroll
    for (int s = 0; s < 4; ++s)
#pragma unroll
        for (int j = 0; j < 8; ++j) {
            int d  = s * 32 + quad * 8 + j;
            int kp = kptile * 16 + mrow;
            int k  = kp >> 1;
            float ang = TWO_PI_OVER_128 * (float)((k * d) & 127);
            float v = (kp & 1) ? -sinf(ang) : cosf(ang);
            Ff[s][j] = (_Float16)v;
        }

    // ---- mix accumulators: wave wv owns k = {2wv, 2wv+1}; Z2[o' 0..127][t 0..15] ----
    // acc[kk][m][r]: o' = m*16 + quad*4 + r, t = mrow  (MFMA C layout)
    floatx4 acc[2][8];
#pragma unroll
    for (int kk = 0; kk < 2; ++kk)
#pragma unroll
        for (int m = 0; m < 8; ++m)
            acc[kk][m] = (floatx4){0.f, 0.f, 0.f, 0.f};

    // w layout [i][o][k][2] f32: addr = i*4096 + o*64 + k*2 (+comp)
    const float* wbase = wt + (quad * 2) * 4096 + (mrow >> 1) * 64 + wv * 4;
    const int a_im = mrow & 1;   // A-row parity: 0 = re row, 1 = im row

    // ---- prologue: stage chunk 0 into Xs ----
    if (BR == 0) {
#pragma unroll
        for (int p = 0; p < 4; ++p) {
            int idx = p * 1024 + tid;
            int col = idx >> 5, dg = idx & 31;
            int i = col >> 4, t = col & 15;
            const float4 v = *(const float4*)(x + xb + (long)i * 16384 + t * 128 + dg * 4);
            *(uint2*)&Xs[col * 136 + dg * 4] = make_uint2(packh2(v.x, v.y), packh2(v.z, v.w));
        }
    } else {
#pragma unroll
        for (int p = 0; p < 4; ++p) {
            int i  = (tid >> 9) + p * 2;
            int d  = (tid >> 2) & 127;
            int tq = (tid & 3) * 4;
            const float4 v = *(const float4*)(x + xb + (long)i * 16384 + d * 128 + tq);
            int colb = i * 16 + tq;
            Xs[(colb + 0) * 136 + d] = __builtin_bit_cast(unsigned short, (_Float16)v.x);
            Xs[(colb + 1) * 136 + d] = __builtin_bit_cast(unsigned short, (_Float16)v.y);
            Xs[(colb + 2) * 136 + d] = __builtin_bit_cast(unsigned short, (_Float16)v.z);
            Xs[(colb + 3) * 136 + d] = __builtin_bit_cast(unsigned short, (_Float16)v.w);
        }
    }
    __syncthreads();

    // ================= chunk loop: 8 chunks x 8 input channels =================
    for (int c = 0; c < 8; ++c) {
        // ---------- stage 1: Y = F x X -> Ys[k][t][r=2i+c] ----------
#pragma unroll
        for (int cc = 0; cc < 2; ++cc) {
            int i = (wv >> 2) * 2 + cc;
            floatx4 y4 = {0.f, 0.f, 0.f, 0.f};
#pragma unroll
            for (int s = 0; s < 4; ++s) {
                uint4 bv = *(const uint4*)&Xs[(i * 16 + mrow) * 136 + s * 32 + quad * 8];
                y4 = __builtin_amdgcn_mfma_f32_16x16x32_f16(Ff[s], ash8(bv), y4, 0, 0, 0);
            }
            // C layout: t = mrow, kp = kptile*16 + quad*4 + r  -> k0 = kp>>1, (re,im) pairs
            int k0 = kptile * 8 + quad * 2;
            unsigned int* yw = (unsigned int*)Ys;
            yw[(k0    ) * (YS_PK / 2) + mrow * (YS_PR / 2) + i] = packh2(y4[0], y4[1]);
            yw[(k0 + 1) * (YS_PK / 2) + mrow * (YS_PR / 2) + i] = packh2(y4[2], y4[3]);
        }
        __syncthreads();   // Ys ready; Xs reads done

        // ---------- prefetch next chunk's x into regs (hides under mix) ----------
        float4 pf[4];
        if (c < 7) {
            if (BR == 0) {
#pragma unroll
                for (int p = 0; p < 4; ++p) {
                    int idx = p * 1024 + tid;
                    int col = idx >> 5, dg = idx & 31;
                    int i = col >> 4, t = col & 15;
                    pf[p] = *(const float4*)(x + xb + (long)((c + 1) * 8 + i) * 16384 + t * 128 + dg * 4);
                }
            } else {
#pragma unroll
                for (int p = 0; p < 4; ++p) {
                    int i  = (tid >> 9) + p * 2;
                    int d  = (tid >> 2) & 127;
                    int tq = (tid & 3) * 4;
                    pf[p] = *(const float4*)(x + xb + (long)((c + 1) * 8 + i) * 16384 + d * 128 + tq);
                }
            }
        }

        // ---------- mix (MFMA): per k, Z2 += W2 x Y2 ----------
        {
            // B fragments: rows r = quad*4+j, col t = mrow — one b64 per k
            half4v bf0 = ash4(*(const uint2*)&Ys[(wv * 2    ) * YS_PK + mrow * YS_PR + quad * 4]);
            half4v bf1 = ash4(*(const uint2*)&Ys[(wv * 2 + 1) * YS_PK + mrow * YS_PR + quad * 4]);
            const float* wc = wbase + c * 32768;
#pragma unroll
            for (int m = 0; m < 8; ++m) {
                // float4 = (re,im) for k0 and k1 at channel i0 = c*8 + quad*2 (+1)
                const float4 wA = *(const float4*)(wc + m * 512);
                const float4 wB = *(const float4*)(wc + 4096 + m * 512);
                // A row o' = m*16 + mrow; re row: (re,-im), im row: (im,re)
                float s00 = a_im ? wA.y :  wA.x;
                float s01 = a_im ? wA.x : -wA.y;
                float s02 = a_im ? wB.y :  wB.x;
                float s03 = a_im ? wB.x : -wB.y;
                float s10 = a_im ? wA.w :  wA.z;
                float s11 = a_im ? wA.z : -wA.w;
                float s12 = a_im ? wB.w :  wB.z;
                float s13 = a_im ? wB.z : -wB.w;
                uint2 a0u = make_uint2(packh2(s00, s01), packh2(s02, s03));
                uint2 a1u = make_uint2(packh2(s10, s11), packh2(s12, s13));
                acc[0][m] = MFMA_K16(ash4(a0u), bf0, acc[0][m]);
                acc[1][m] = MFMA_K16(ash4(a1u), bf1, acc[1][m]);
            }
        }

        // ---------- write prefetched chunk into Xs ----------
        if (c < 7) {
            if (BR == 0) {
#pragma unroll
                for (int p = 0; p < 4; ++p) {
                    int idx = p * 1024 + tid;
                    int col = idx >> 5, dg = idx & 31;
                    *(uint2*)&Xs[col * 136 + dg * 4] =
                        make_uint2(packh2(pf[p].x, pf[p].y), packh2(pf[p].z, pf[p].w));
                }
            } else {
#pragma unroll
                for (int p = 0; p < 4; ++p) {
                    int d  = (tid >> 2) & 127;
                    int tq = (tid & 3) * 4;
                    int colb = ((tid >> 9) + p * 2) * 16 + tq;
                    Xs[(colb + 0) * 136 + d] = __builtin_bit_cast(unsigned short, (_Float16)pf[p].x);
                    Xs[(colb + 1) * 136 + d] = __builtin_bit_cast(unsigned short, (_Float16)pf[p].y);
                    Xs[(colb + 2) * 136 + d] = __builtin_bit_cast(unsigned short, (_Float16)pf[p].z);
                    Xs[(colb + 3) * 136 + d] = __builtin_bit_cast(unsigned short, (_Float16)pf[p].w);
                }
            }
        }
        __syncthreads();   // Xs(c+1) ready; Ys(c) reads done
    }

    // ================= stage 3: out = G x Z, quarter of o at a time =================
    const int dt  = wv & 7;
    const int ctb = (wv >> 3) * 8;
    const int dp  = dt * 16 + mrow;
    half8 Gf[2];
#pragma unroll
    for (int s = 0; s < 2; ++s)
#pragma unroll
        for (int j = 0; j < 8; ++j) {
            int kp = s * 32 + quad * 8 + j;
            int k  = kp >> 1;
            float ang = TWO_PI_OVER_128 * (float)((k * dp) & 127);
            float v;
            if (kp == 0)      v = 1.f / 128.f;
            else if (kp == 1) v = 0.f;                       // irfft drops DC imag
            else v = (kp & 1) ? -(2.f / 128.f) * sinf(ang) : (2.f / 128.f) * cosf(ang);
            Gf[s][j] = (_Float16)v;
        }

    for (int q = 0; q < 4; ++q) {
        __syncthreads();   // prev quarter's Zs reads (or chunk-7 traffic) done
        // write Zs from acc: quarter q <-> m in {2q, 2q+1}
        // o' = m*16 + quad*4 + r -> o = 16q + mm*8 + quad*2 + (r>>1), comp = r&1
        // slot = k ^ 8*quad; reader XORs the same value (col>>4 parity bits), so it cancels
#pragma unroll
        for (int mm = 0; mm < 2; ++mm) {
            const int m = q * 2 + mm;
#pragma unroll
            for (int kk = 0; kk < 2; ++kk) {
                const int slot = (wv * 2 + kk) ^ (quad * 8);
                const int col  = (mm * 8 + quad * 2) * 16 + mrow;
                Zs[ col       * 36 + slot] = packh2(acc[kk][m][0], acc[kk][m][1]);
                Zs[(col + 16) * 36 + slot] = packh2(acc[kk][m][2], acc[kk][m][3]);
            }
        }
        __syncthreads();   // Zs ready

#pragma unroll
        for (int cc = 0; cc < 8; ++cc) {
            const int ct  = ctb + cc;
            const int col = ct * 16 + mrow;
            const int swz = (ct & 6) << 2;
            floatx4 o4 = {0.f, 0.f, 0.f, 0.f};
#pragma unroll
            for (int s = 0; s < 2; ++s) {
                uint4 zv = *(const uint4*)&Zs[col * 36 + ((s * 16 + quad * 4) ^ swz)];
                o4 = __builtin_amdgcn_mfma_f32_16x16x32_f16(Gf[s], ash8(zv), o4, 0, 0, 0);
            }
            const int oo = q * 16 + ct;
            const int t  = mrow;
            const int db = dt * 16 + quad * 4;
            if (BR == 0) {
                *(float4*)(out + ob + (long)oo * 16384 + t * 128 + db) =
                    make_float4(o4[0], o4[1], o4[2], o4[3]);
            } else {
                float* p = out + ob + (long)oo * 16384 + (long)db * 128 + t;
                p[0]   += o4[0];
                p[128] += o4[1];
                p[256] += o4[2];
                p[384] += o4[3];
            }
        }
    }
}

extern "C" void kernel_launch(void* const* d_in, const int* in_sizes, int n_in,
                              void* d_out, int out_size, void* d_ws, size_t ws_size,
                              hipStream_t stream) {
    const float* x  = (const float*)d_in[0];
    const float* w0 = (const float*)d_in[1];
    const float* w1 = (const float*)d_in[2];
    float* out = (float*)d_out;

    dim3 grid(256);    // 32 batches x 8 line-tiles
    dim3 block(1024);

    spectral<0><<<grid, block, 0, stream>>>(x, w0, out);   // width branch: writes out
    spectral<1><<<grid, block, 0, stream>>>(x, w1, out);   // height branch: accumulates
}